// Round 4
// baseline (32.607 us; speedup 1.0000x reference)
//
#include <hip/hip_runtime.h>

#define NS 8192
#define NC 512
#define NF 128

typedef short short8 __attribute__((ext_vector_type(8)));
typedef float f32x4 __attribute__((ext_vector_type(4)));

static __device__ __forceinline__ unsigned short f2bf(float f) {
    unsigned u = __float_as_uint(f);
    return (unsigned short)((u + 0x7fffu + ((u >> 16) & 1u)) >> 16);   // RNE
}

static __device__ __forceinline__ short8 pack8(const float* p) {
    float4 v0 = *(const float4*)p;
    float4 v1 = *(const float4*)(p + 4);
    short8 o;
    o[0] = (short)f2bf(v0.x); o[1] = (short)f2bf(v0.y);
    o[2] = (short)f2bf(v0.z); o[3] = (short)f2bf(v0.w);
    o[4] = (short)f2bf(v1.x); o[5] = (short)f2bf(v1.y);
    o[6] = (short)f2bf(v1.z); o[7] = (short)f2bf(v1.w);
    return o;
}

// One block = 32 samples. Everything fused:
//   LT unpack (LDS) -> U = X@L (MFMA) + q_x -> loop 4 chunks of 128 centers:
//   V = C@L (MFMA, recomputed per block) + q_c -> cross = U V^T (MFMA) -> exp epilogue.
__global__ __launch_bounds__(512) void fused_kernel(const float* __restrict__ X,
                                                    const float* __restrict__ pe,
                                                    const float* __restrict__ centers,
                                                    const float* __restrict__ w,
                                                    float* __restrict__ out) {
    __shared__ short LT[NF * NF];       // 32 KB  L^T bf16, XOR-swizzled (granule 8 elems)
    __shared__ short Ulds[32 * NF];     // 8 KB   U bf16, swizzled
    __shared__ short Vlds[NF * NF];     // 32 KB  V chunk (128 centers) bf16, swizzled
    __shared__ float qxlds[8][32];
    __shared__ float qxfin[32];
    __shared__ float qcsh[NF];
    __shared__ float outlds[8][32];

    int t = threadIdx.x;
    int wv = t >> 6, lane = t & 63, g = lane >> 4, r = lane & 15;
    int n0 = blockIdx.x * 32;

    // X A-fragments (fp32 -> bf16 in-register): rows n0+16s+r, k-chunk kk*32+8g
    short8 a[2][4];
#pragma unroll
    for (int s = 0; s < 2; ++s)
#pragma unroll
        for (int kk = 0; kk < 4; ++kk)
            a[s][kk] = pack8(&X[(size_t)(n0 + 16 * s + r) * NF + kk * 32 + 8 * g]);

    // prefetch chunk-0 center fragments (rows 16wv+r)
    short8 av[2][4];
#pragma unroll
    for (int kk = 0; kk < 4; ++kk)
        av[0][kk] = pack8(&centers[(size_t)(16 * wv + r) * NF + kk * 32 + 8 * g]);

    // unpack L^T -> LDS (bf16, swizzled): LT[j][i] = L[i][j], elem at [j*128 + (i ^ ((j&7)<<3))]
    for (int idx = t; idx < NF * NF; idx += 512) {
        int j = idx >> 7, i = idx & 127;
        float v = (j <= i) ? pe[i * (i + 1) / 2 + j] : 0.f;
        LT[j * NF + (i ^ ((j & 7) << 3))] = (short)f2bf(v);
    }
    __syncthreads();

    // ---------- U = X@L : wave wv computes f-cols [16wv, 16wv+16)
    f32x4 aq[2];
    aq[0] = (f32x4){0.f, 0.f, 0.f, 0.f};
    aq[1] = (f32x4){0.f, 0.f, 0.f, 0.f};
#pragma unroll
    for (int kk = 0; kk < 4; ++kk) {
        int row = 16 * wv + r;
        short8 bf = *(const short8*)&LT[row * NF + ((kk * 32 + 8 * g) ^ ((row & 7) << 3))];
        aq[0] = __builtin_amdgcn_mfma_f32_16x16x32_bf16(a[0][kk], bf, aq[0], 0, 0, 0);
        aq[1] = __builtin_amdgcn_mfma_f32_16x16x32_bf16(a[1][kk], bf, aq[1], 0, 0, 0);
    }
#pragma unroll
    for (int s = 0; s < 2; ++s)
#pragma unroll
        for (int reg = 0; reg < 4; ++reg) {
            int rr = 16 * s + 4 * g + reg;            // sample row; col = 16wv + r
            float x = aq[s][reg];
            Ulds[rr * NF + ((16 * wv + r) ^ ((rr & 7) << 3))] = (short)f2bf(x);
            float v = x * x;
            v += __shfl_xor(v, 1); v += __shfl_xor(v, 2);
            v += __shfl_xor(v, 4); v += __shfl_xor(v, 8);
            if (r == 0) qxlds[wv][rr] = v;
        }
    __syncthreads();
    if (t < 32) {
        float s = 0.f;
#pragma unroll
        for (int i = 0; i < 8; ++i) s += qxlds[i][t];
        qxfin[t] = s;                                  // visible to all after next sync
    }
    // U A-fragments from LDS
    short8 a2[2][4];
#pragma unroll
    for (int s = 0; s < 2; ++s)
#pragma unroll
        for (int kk = 0; kk < 4; ++kk) {
            int row = 16 * s + r;
            a2[s][kk] = *(const short8*)&Ulds[row * NF + ((kk * 32 + 8 * g) ^ ((row & 7) << 3))];
        }

    const float HL2E = 0.72134752044448169f;   // 0.5*log2(e)
    float rs[2][4] = {};

#pragma unroll
    for (int ch = 0; ch < 4; ++ch) {
        int p = ch & 1;
        // ----- V chunk: wave wv computes center rows [16wv,16wv+16) x all 128 f
        f32x4 vacc[8];
#pragma unroll
        for (int ct = 0; ct < 8; ++ct) vacc[ct] = (f32x4){0.f, 0.f, 0.f, 0.f};
#pragma unroll
        for (int kk = 0; kk < 4; ++kk)
#pragma unroll
            for (int ct = 0; ct < 8; ++ct) {
                int fr = 16 * ct + r;                  // f col (LT row)
                short8 bf = *(const short8*)&LT[fr * NF + ((kk * 32 + 8 * g) ^ ((fr & 7) << 3))];
                vacc[ct] = __builtin_amdgcn_mfma_f32_16x16x32_bf16(av[p][kk], bf, vacc[ct], 0, 0, 0);
            }
        // write V chunk to LDS (swizzled) + q_c from fp32 accumulators
#pragma unroll
        for (int reg = 0; reg < 4; ++reg) {
            int cl = 16 * wv + 4 * g + reg;            // chunk-local center row
            float s2 = 0.f;
#pragma unroll
            for (int ct = 0; ct < 8; ++ct) {
                float x = vacc[ct][reg];
                Vlds[cl * NF + ((16 * ct + r) ^ ((cl & 7) << 3))] = (short)f2bf(x);
                s2 = fmaf(x, x, s2);
            }
            s2 += __shfl_xor(s2, 1); s2 += __shfl_xor(s2, 2);
            s2 += __shfl_xor(s2, 4); s2 += __shfl_xor(s2, 8);
            if (r == 0) qcsh[cl] = s2;
        }
        __syncthreads();
        // prefetch next chunk's center fragments (overlaps cross MFMA)
        if (ch < 3) {
#pragma unroll
            for (int kk = 0; kk < 4; ++kk)
                av[p ^ 1][kk] = pack8(&centers[(size_t)((ch + 1) * 128 + 16 * wv + r) * NF + kk * 32 + 8 * g]);
        }
        // ----- cross: wave wv vs chunk centers [16wv, 16wv+16)
        f32x4 acc[2];
        acc[0] = (f32x4){0.f, 0.f, 0.f, 0.f};
        acc[1] = (f32x4){0.f, 0.f, 0.f, 0.f};
#pragma unroll
        for (int kk = 0; kk < 4; ++kk) {
            int vr = 16 * wv + r;
            short8 bf = *(const short8*)&Vlds[vr * NF + ((kk * 32 + 8 * g) ^ ((vr & 7) << 3))];
            acc[0] = __builtin_amdgcn_mfma_f32_16x16x32_bf16(a2[0][kk], bf, acc[0], 0, 0, 0);
            acc[1] = __builtin_amdgcn_mfma_f32_16x16x32_bf16(a2[1][kk], bf, acc[1], 0, 0, 0);
        }
        float qcv = qcsh[16 * wv + r];
        float wvv = w[ch * 128 + 16 * wv + r];
#pragma unroll
        for (int s = 0; s < 2; ++s)
#pragma unroll
            for (int reg = 0; reg < 4; ++reg) {
                float e = (2.f * acc[s][reg] - qxfin[16 * s + 4 * g + reg] - qcv) * HL2E;
                rs[s][reg] = fmaf(exp2f(e), wvv, rs[s][reg]);
            }
        if (ch < 3) __syncthreads();   // protect Vlds/qcsh before next chunk overwrites
    }

    // ----- final reduce over waves
#pragma unroll
    for (int s = 0; s < 2; ++s)
#pragma unroll
        for (int reg = 0; reg < 4; ++reg) {
            float v = rs[s][reg];
            v += __shfl_xor(v, 1); v += __shfl_xor(v, 2);
            v += __shfl_xor(v, 4); v += __shfl_xor(v, 8);
            if (r == 0) outlds[wv][16 * s + 4 * g + reg] = v;
        }
    __syncthreads();
    if (t < 32) {
        float s = 0.f;
#pragma unroll
        for (int i = 0; i < 8; ++i) s += outlds[i][t];
        out[n0 + t] = s;
    }
}

extern "C" void kernel_launch(void* const* d_in, const int* in_sizes, int n_in,
                              void* d_out, int out_size, void* d_ws, size_t ws_size,
                              hipStream_t stream) {
    const float* X       = (const float*)d_in[0];
    const float* pe      = (const float*)d_in[1];
    const float* centers = (const float*)d_in[2];
    const float* w       = (const float*)d_in[3];
    float* out = (float*)d_out;
    (void)d_ws; (void)ws_size; (void)in_sizes; (void)n_in; (void)out_size;

    fused_kernel<<<256, 512, 0, stream>>>(X, pe, centers, w, out);
}

// Round 5
// 29.955 us; speedup vs baseline: 1.0885x; 1.0885x over previous
//
#include <hip/hip_runtime.h>

#define NS 8192
#define NC 512
#define NF 128

typedef short short8 __attribute__((ext_vector_type(8)));
typedef short short4v __attribute__((ext_vector_type(4)));
typedef float f32x4 __attribute__((ext_vector_type(4)));

static __device__ __forceinline__ unsigned short f2bf(float f) {
    unsigned u = __float_as_uint(f);
    return (unsigned short)((u + 0x7fffu + ((u >> 16) & 1u)) >> 16);   // RNE
}

static __device__ __forceinline__ short8 pack8(const float* p) {
    float4 v0 = *(const float4*)p;
    float4 v1 = *(const float4*)(p + 4);
    short8 o;
    o[0] = (short)f2bf(v0.x); o[1] = (short)f2bf(v0.y);
    o[2] = (short)f2bf(v0.z); o[3] = (short)f2bf(v0.w);
    o[4] = (short)f2bf(v1.x); o[5] = (short)f2bf(v1.y);
    o[6] = (short)f2bf(v1.z); o[7] = (short)f2bf(v1.w);
    return o;
}

// Swizzled element address in a [128][128] bf16 LDS tile:
//   short index = row*128 + (((col>>3) ^ (row&7))<<3) + (col&7)
// b128 reads with row = 16*s + r are then 2-way (free) bank aliased.

// One block = 128 samples x 128 centers output tile. 16 waves (4/SIMD).
// wave wv: wg = wv>>3 picks row-half (tiles 4wg..4wg+3), wf = wv&7 picks col-tile.
__global__ __launch_bounds__(1024) void fused_tile_kernel(const float* __restrict__ X,
                                                          const float* __restrict__ pe,
                                                          const float* __restrict__ centers,
                                                          const float* __restrict__ w,
                                                          float* __restrict__ out) {
    __shared__ __align__(16) char smem[114816];
    short* LT     = (short*)(smem);             // 32 KB: L^T, later overwritten by Vlds
    short* Vlds   = (short*)(smem);
    short* Xlds   = (short*)(smem + 32768);     // 32 KB: X tile, then centers tile
    short* Ulds   = (short*)(smem + 65536);     // 32 KB: U = X@L (bf16)
    short* packed = (short*)(smem + 98304);     // 16.5 KB packed tril(pe) bf16 (dead after scatter)
    float* qxw    = (float*)(smem + 98304);     // 4 KB  [8][128]  (reuses packed region)
    float* qcw    = (float*)(smem + 102400);    // 4 KB  [8][128]
    float* outw   = (float*)(smem + 106496);    // 4 KB  [8][128]
    float* qxfin  = (float*)(smem + 110592);    // 512 B
    float* qcfin  = (float*)(smem + 111104);    // 512 B

    int t = threadIdx.x;
    int wv = t >> 6, lane = t & 63, g = lane >> 4, r = lane & 15;
    int wg = wv >> 3, wf = wv & 7;
    int swz = r & 7;
    int b = blockIdx.x;
    int sb = b & 63, cb = b >> 6;       // cb-siblings (same sb) differ by 64 -> same XCD (b%8)
    int n0 = sb * 128, c0 = cb * 128;

    // ---- stage X tile -> Xlds (bf16, swizzled); pe -> packed (bf16, linear, coalesced)
    {
        int row = t >> 3, seg = t & 7;
        const float* src = X + (size_t)(n0 + row) * NF + seg * 16;
        short8* dst = (short8*)Xlds;
#pragma unroll
        for (int q = 0; q < 2; ++q)
            dst[row * 16 + ((seg * 2 + q) ^ (row & 7))] = pack8(src + q * 8);
    }
    {
        const float4* pe4 = (const float4*)pe;
        for (int c = t; c < 2064; c += 1024) {      // 8256 floats = 2064 float4
            float4 v = pe4[c];
            short4v o;
            o[0] = (short)f2bf(v.x); o[1] = (short)f2bf(v.y);
            o[2] = (short)f2bf(v.z); o[3] = (short)f2bf(v.w);
            ((short4v*)packed)[c] = o;
        }
    }
    __syncthreads();
    // ---- scatter LT[j][i] = L[i][j] from LDS-packed (no global gather)
    for (int idx = t; idx < NF * NF; idx += 1024) {
        int j = idx >> 7, i = idx & 127;
        short v = (j <= i) ? packed[i * (i + 1) / 2 + j] : (short)0;
        LT[j * NF + (((i >> 3) ^ (j & 7)) << 3) + (i & 7)] = v;
    }
    __syncthreads();

    // ---- B-frags of L^T for f-cols [16wf, 16wf+16)  (shared by U and V phases)
    short8 bb[4];
    {
        const short8* A8 = (const short8*)LT;
#pragma unroll
        for (int kk = 0; kk < 4; ++kk)
            bb[kk] = A8[(16 * wf + r) * 16 + ((kk * 4 + g) ^ swz)];
    }
    // ---- U = X @ L : sample tiles 4wg..4wg+3, f-cols [16wf,16wf+16)
    f32x4 acc[4];
#pragma unroll
    for (int s = 0; s < 4; ++s) acc[s] = (f32x4){0.f, 0.f, 0.f, 0.f};
    {
        const short8* X8 = (const short8*)Xlds;
#pragma unroll
        for (int s = 0; s < 4; ++s) {
            int row = 16 * (4 * wg + s) + r;
#pragma unroll
            for (int kk = 0; kk < 4; ++kk) {
                short8 a = X8[row * 16 + ((kk * 4 + g) ^ swz)];
                acc[s] = __builtin_amdgcn_mfma_f32_16x16x32_bf16(a, bb[kk], acc[s], 0, 0, 0);
            }
        }
    }
    // qx partials (sum over this wave's 16 f-cols) + U -> Ulds (bf16, swizzled)
#pragma unroll
    for (int s = 0; s < 4; ++s)
#pragma unroll
        for (int reg = 0; reg < 4; ++reg) {
            int row = 16 * (4 * wg + s) + 4 * g + reg;
            int col = 16 * wf + r;
            float x = acc[s][reg];
            Ulds[row * NF + (((col >> 3) ^ (row & 7)) << 3) + (col & 7)] = (short)f2bf(x);
            float v = x * x;
            v += __shfl_xor(v, 1); v += __shfl_xor(v, 2);
            v += __shfl_xor(v, 4); v += __shfl_xor(v, 8);
            if (r == 0) qxw[wf * NF + row] = v;
        }
    __syncthreads();
    if (t < NF) {
        float s = 0.f;
#pragma unroll
        for (int i = 0; i < 8; ++i) s += qxw[i * NF + t];
        qxfin[t] = s;
    }
    // ---- stage centers tile into Xlds (Xlds dead after U MFMAs; sync above covers)
    {
        int row = t >> 3, seg = t & 7;
        const float* src = centers + (size_t)(c0 + row) * NF + seg * 16;
        short8* dst = (short8*)Xlds;
#pragma unroll
        for (int q = 0; q < 2; ++q)
            dst[row * 16 + ((seg * 2 + q) ^ (row & 7))] = pack8(src + q * 8);
    }
    __syncthreads();
    // ---- V = C @ L : center tiles 4wg..4wg+3; write into Vlds (over LT; bb is in regs)
    f32x4 vacc[4];
#pragma unroll
    for (int s = 0; s < 4; ++s) vacc[s] = (f32x4){0.f, 0.f, 0.f, 0.f};
    {
        const short8* C8 = (const short8*)Xlds;
#pragma unroll
        for (int s = 0; s < 4; ++s) {
            int row = 16 * (4 * wg + s) + r;
#pragma unroll
            for (int kk = 0; kk < 4; ++kk) {
                short8 a = C8[row * 16 + ((kk * 4 + g) ^ swz)];
                vacc[s] = __builtin_amdgcn_mfma_f32_16x16x32_bf16(a, bb[kk], vacc[s], 0, 0, 0);
            }
        }
    }
#pragma unroll
    for (int s = 0; s < 4; ++s)
#pragma unroll
        for (int reg = 0; reg < 4; ++reg) {
            int row = 16 * (4 * wg + s) + 4 * g + reg;   // center-local row
            int col = 16 * wf + r;                       // f col
            float x = vacc[s][reg];
            Vlds[row * NF + (((col >> 3) ^ (row & 7)) << 3) + (col & 7)] = (short)f2bf(x);
            float v = x * x;
            v += __shfl_xor(v, 1); v += __shfl_xor(v, 2);
            v += __shfl_xor(v, 4); v += __shfl_xor(v, 8);
            if (r == 0) qcw[wf * NF + row] = v;
        }
    __syncthreads();
    if (t < NF) {
        float s = 0.f;
#pragma unroll
        for (int i = 0; i < 8; ++i) s += qcw[i * NF + t];
        qcfin[t] = s;
    }
    __syncthreads();
    // ---- cross = U @ V^T : wave covers center-tile wf, sample tiles 4wg..4wg+3
    short8 bc[4];
    {
        const short8* V8 = (const short8*)Vlds;
#pragma unroll
        for (int kk = 0; kk < 4; ++kk)
            bc[kk] = V8[(16 * wf + r) * 16 + ((kk * 4 + g) ^ swz)];
    }
    f32x4 acc2[4];
#pragma unroll
    for (int s = 0; s < 4; ++s) acc2[s] = (f32x4){0.f, 0.f, 0.f, 0.f};
    {
        const short8* U8 = (const short8*)Ulds;
#pragma unroll
        for (int s = 0; s < 4; ++s) {
            int row = 16 * (4 * wg + s) + r;
#pragma unroll
            for (int kk = 0; kk < 4; ++kk) {
                short8 a = U8[row * 16 + ((kk * 4 + g) ^ swz)];
                acc2[s] = __builtin_amdgcn_mfma_f32_16x16x32_bf16(a, bc[kk], acc2[s], 0, 0, 0);
            }
        }
    }
    // ---- epilogue: exp2 + weights + reduce over 16 centers (lanes) per wave
    float wl = w[c0 + 16 * wf + r];
    float qcl = qcfin[16 * wf + r];
    const float HL2E = 0.72134752044448169f;   // 0.5*log2(e)
#pragma unroll
    for (int s = 0; s < 4; ++s)
#pragma unroll
        for (int reg = 0; reg < 4; ++reg) {
            int row = 16 * (4 * wg + s) + 4 * g + reg;
            float e = (2.f * acc2[s][reg] - qxfin[row] - qcl) * HL2E;
            float v = exp2f(e) * wl;
            v += __shfl_xor(v, 1); v += __shfl_xor(v, 2);
            v += __shfl_xor(v, 4); v += __shfl_xor(v, 8);
            if (r == 0) outw[wf * NF + row] = v;
        }
    __syncthreads();
    if (t < NF) {
        float s = 0.f;
#pragma unroll
        for (int i = 0; i < 8; ++i) s += outw[i * NF + t];
        atomicAdd(&out[n0 + t], s);      // 4 center-group blocks contribute per sample
    }
}

extern "C" void kernel_launch(void* const* d_in, const int* in_sizes, int n_in,
                              void* d_out, int out_size, void* d_ws, size_t ws_size,
                              hipStream_t stream) {
    const float* X       = (const float*)d_in[0];
    const float* pe      = (const float*)d_in[1];
    const float* centers = (const float*)d_in[2];
    const float* w       = (const float*)d_in[3];
    float* out = (float*)d_out;
    (void)d_ws; (void)ws_size; (void)in_sizes; (void)n_in;

    // out is poisoned by the harness; atomics need zeros. Memset node is graph-capturable.
    hipMemsetAsync(out, 0, (size_t)out_size * sizeof(float), stream);
    fused_tile_kernel<<<256, 1024, 0, stream>>>(X, pe, centers, w, out);
}